// Round 3
// baseline (153.058 us; speedup 1.0000x reference)
//
#include <hip/hip_runtime.h>
#include <hip/hip_bf16.h>

typedef __bf16 bf16x8 __attribute__((ext_vector_type(8)));
typedef __bf16 bf16x4 __attribute__((ext_vector_type(4)));
typedef float f32x4 __attribute__((ext_vector_type(4)));

#define MFMA16(a, b, c) __builtin_amdgcn_mfma_f32_16x16x32_bf16((a), (b), (c), 0, 0, 0)

constexpr int kB = 4096, kN = 49, kC = 128;
constexpr float kScale = 0.17677669529663687f;  // 32^-0.5

// workspace layout (bytes)
constexpr size_t WQ_OFF = 0;        // qkv_w packed bf16: [24][4][64][8] = 98304 B
constexpr size_t WP_OFF = 98304;    // proj_w packed bf16: [8][4][64][8] = 32768 B
constexpr size_t BP_OFF = 131072;   // bias padded f32 [4][64][64] (fallback) = 65536 B
constexpr size_t CM_OFF = 196608;   // combined bias+mask f32 [64][4][64cc][64r] = 4 MiB
constexpr size_t CM_BYTES = (size_t)64 * 4 * 64 * 64 * 4;
constexpr size_t WS_NEED = CM_OFF + CM_BYTES;

// ---------------------------------------------------------------------------
// prep: repack weights bf16 fragment-linear; gather bias; build bias+mask table
// ---------------------------------------------------------------------------
__global__ void prep_kernel(const float* __restrict__ qkv_w,
                            const float* __restrict__ proj_w,
                            const float* __restrict__ bias_table,
                            const int* __restrict__ rel_raw,
                            const float* __restrict__ maskp,
                            __bf16* __restrict__ wq, __bf16* __restrict__ wp,
                            float* __restrict__ biasp, float* __restrict__ cm) {
  const int blk = blockIdx.x, t = threadIdx.x;
  // int64-vs-int32 sniff: elem0=84 -> int64 word1 is 0; int32 word1 = rel[1]=83
  const bool is64 = (rel_raw[1] == 0);
  if (blk < 24) {  // qkv_w pack
    const int kk = t >> 6, lane = t & 63;
    const int k0 = kk * 32 + ((lane >> 4) << 3);
    const int c  = blk * 16 + (lane & 15);
#pragma unroll
    for (int i = 0; i < 8; ++i)
      wq[((blk * 4 + kk) * 64 + lane) * 8 + i] = (__bf16)qkv_w[(k0 + i) * 384 + c];
  } else if (blk < 32) {  // proj_w pack
    const int nt = blk - 24;
    const int kk = t >> 6, lane = t & 63;
    const int k0 = kk * 32 + ((lane >> 4) << 3);
    const int c  = nt * 16 + (lane & 15);
#pragma unroll
    for (int i = 0; i < 8; ++i)
      wp[((nt * 4 + kk) * 64 + lane) * 8 + i] = (__bf16)proj_w[(k0 + i) * 128 + c];
  } else if (blk < 96) {  // biasp [h][r][cc] fallback table
    const int e = (blk - 32) * 256 + t;
    const int h = e >> 12, i = (e >> 6) & 63, j = e & 63;
    float v = 0.f;
    if (i < kN && j < kN) {
      const int flat = i * kN + j;
      const int idx = is64 ? rel_raw[2 * flat] : rel_raw[flat];
      v = bias_table[idx * 4 + h];
    }
    biasp[(h * 64 + i) * 64 + j] = v;
  } else {  // combined table cm[wm][h][cc][r]
    const int e = (blk - 96) * 256 + t;  // 0..2^20-1
    const int wm = e >> 14, h = (e >> 12) & 3, cc = (e >> 6) & 63, r = e & 63;
    float v = 0.f;
    if (r < kN && cc < kN) {
      const int flat = r * kN + cc;
      const int idx = is64 ? rel_raw[2 * flat] : rel_raw[flat];
      v = bias_table[idx * 4 + h] + maskp[wm * (kN * kN) + flat];
    }
    cm[(((size_t)(wm * 4 + h)) << 12) + (cc << 6) + r] = v;
  }
}

// ---------------------------------------------------------------------------
// fused window attention: 1 block = 1 window, 4 waves = 4 heads, 3 blocks/CU
// ---------------------------------------------------------------------------
template <bool USE_CM>
__global__ __launch_bounds__(256, 3)
void wattn_fused(const float* __restrict__ x, const float* __restrict__ mask,
                 const float* __restrict__ qkv_b, const float* __restrict__ proj_b,
                 const __bf16* __restrict__ wq, const __bf16* __restrict__ wp,
                 const float* __restrict__ biasp, const float* __restrict__ cm,
                 float* __restrict__ out) {
  constexpr int QS = 40, VS = 72, PS = 72, OBS = 136, QR = 56;

  __shared__ __align__(16) char smem[54272];
  __bf16* qs = (__bf16*)smem;              // [4][56][40]  (17920 B)
  __bf16* ks = (__bf16*)(smem + 17920);    // [4][56][40]  (17920 B)
  __bf16* vt = (__bf16*)(smem + 35840);    // [4][32][72]  (18432 B)
  __bf16* ps = (__bf16*)smem;              // overlay [4][56][72] (after B2)
  __bf16* ob = (__bf16*)smem;              // overlay [49..64][136] (after B3)

  const int tid = threadIdx.x;
  const int w = tid >> 6, lane = tid & 63, lg = lane >> 4, lm = lane & 15;
  const int b = blockIdx.x;
  const f32x4 zero4 = {0.f, 0.f, 0.f, 0.f};

  // ---- phase 1: A-fragments straight from global x (f32 -> bf16) ----
  bf16x8 af[4][4];
  {
    const float* xp = x + (size_t)b * (kN * kC);
#pragma unroll
    for (int mt = 0; mt < 4; ++mt) {
      const int r = mt * 16 + lm;
      const float* rp = xp + (r < kN ? r : 0) * kC;
#pragma unroll
      for (int kk = 0; kk < 4; ++kk) {
        f32x4 lo = *(const f32x4*)(rp + kk * 32 + lg * 8);
        f32x4 hi = *(const f32x4*)(rp + kk * 32 + lg * 8 + 4);
        bf16x8 tf, zf;
#pragma unroll
        for (int i2 = 0; i2 < 4; ++i2) { tf[i2] = (__bf16)lo[i2]; tf[4 + i2] = (__bf16)hi[i2]; zf[i2] = (__bf16)0.f; zf[4 + i2] = (__bf16)0.f; }
        af[mt][kk] = (r < kN) ? tf : zf;
      }
    }
  }

  // ---- phase 2: QKV GEMM -> qs/ks/vt (B-frags double-buffered) ----
  {
    const __bf16* wqw = wq + (size_t)(w * 6) * 4 * 64 * 8;
    bf16x8 bcur[4], bnxt[4];
#pragma unroll
    for (int kk = 0; kk < 4; ++kk)
      bcur[kk] = *(const bf16x8*)(wqw + (size_t)(kk * 64 + lane) * 8);
#pragma unroll
    for (int n = 0; n < 6; ++n) {
      if (n < 5) {
#pragma unroll
        for (int kk = 0; kk < 4; ++kk)
          bnxt[kk] = *(const bf16x8*)(wqw + (size_t)(((n + 1) * 4 + kk) * 64 + lane) * 8);
      }
      f32x4 acc[4];
#pragma unroll
      for (int mt = 0; mt < 4; ++mt) acc[mt] = zero4;
#pragma unroll
      for (int kk = 0; kk < 4; ++kk)
#pragma unroll
        for (int mt = 0; mt < 4; ++mt)
          acc[mt] = MFMA16(af[mt][kk], bcur[kk], acc[mt]);

      const int ntg = w * 6 + n;
      const int c = ntg * 16 + lm;
      const int which = c >> 7, h = (c >> 5) & 3, d = c & 31;
      const float qb = qkv_b[c];
      if (which == 0) {
#pragma unroll
        for (int mt = 0; mt < 4; ++mt)
#pragma unroll
          for (int j = 0; j < 4; ++j) {
            const int r = mt * 16 + lg * 4 + j;
            if (r < kN) qs[(h * QR + r) * QS + d] = (__bf16)((acc[mt][j] + qb) * kScale);
          }
      } else if (which == 1) {
#pragma unroll
        for (int mt = 0; mt < 4; ++mt)
#pragma unroll
          for (int j = 0; j < 4; ++j) {
            const int r = mt * 16 + lg * 4 + j;
            if (r < kN) ks[(h * QR + r) * QS + d] = (__bf16)(acc[mt][j] + qb);
          }
      } else {  // vt[h][d][key]
#pragma unroll
        for (int mt = 0; mt < 4; ++mt) {
          const int r0 = mt * 16 + lg * 4;
          bf16x4 pv;
#pragma unroll
          for (int j = 0; j < 4; ++j) pv[j] = (__bf16)(acc[mt][j] + qb);
          *(bf16x4*)(vt + (h * 32 + d) * VS + r0) = pv;
        }
      }
#pragma unroll
      for (int kk = 0; kk < 4; ++kk) bcur[kk] = bnxt[kk];
    }
  }
  __syncthreads();  // B1: qs/ks/vt ready

  // ---- phase 3: S = QK^T + bias + mask, softmax (wave w = head w) ----
  f32x4 s[4][4];
  {
    const int h = w;
    const __bf16* qsh = qs + h * QR * QS;
    const __bf16* ksh = ks + h * QR * QS;
    bf16x8 qf[4], kf[4];
#pragma unroll
    for (int mt = 0; mt < 4; ++mt) qf[mt] = *(const bf16x8*)(qsh + (mt * 16 + lm) * QS + lg * 8);
#pragma unroll
    for (int nt = 0; nt < 4; ++nt) kf[nt] = *(const bf16x8*)(ksh + (nt * 16 + lm) * QS + lg * 8);
#pragma unroll
    for (int mt = 0; mt < 4; ++mt)
#pragma unroll
      for (int nt = 0; nt < 4; ++nt)
        s[mt][nt] = MFMA16(qf[mt], kf[nt], zero4);

    if (USE_CM) {
      const float* cmp = cm + (((size_t)((b & 63) * 4 + h)) << 12);
#pragma unroll
      for (int nt = 0; nt < 4; ++nt) {
        const int cc = nt * 16 + lm;
        const bool vcc = cc < kN;
#pragma unroll
        for (int mt = 0; mt < 4; ++mt) {
          f32x4 bm = *(const f32x4*)(cmp + (cc << 6) + mt * 16 + lg * 4);
#pragma unroll
          for (int j = 0; j < 4; ++j)
            s[mt][nt][j] = vcc ? (s[mt][nt][j] + bm[j]) : -1e30f;
        }
      }
    } else {
      const float* bp = biasp + w * 4096;
      const float* mk = mask + (size_t)(b & 63) * (kN * kN);
#pragma unroll
      for (int mt = 0; mt < 4; ++mt)
#pragma unroll
        for (int nt = 0; nt < 4; ++nt)
#pragma unroll
          for (int j = 0; j < 4; ++j) {
            const int r = mt * 16 + lg * 4 + j, cc = nt * 16 + lm;
            float v = s[mt][nt][j] + bp[(r << 6) + cc];
            if (cc < kN) { if (r < kN) v += mk[r * kN + cc]; } else v = -1e30f;
            s[mt][nt][j] = v;
          }
    }
    // softmax over keys (row = (lg,j); keys spread over lm x nt)
#pragma unroll
    for (int mt = 0; mt < 4; ++mt) {
      f32x4 pm;
#pragma unroll
      for (int j = 0; j < 4; ++j)
        pm[j] = fmaxf(fmaxf(s[mt][0][j], s[mt][1][j]), fmaxf(s[mt][2][j], s[mt][3][j]));
#pragma unroll
      for (int off = 1; off <= 8; off <<= 1)
#pragma unroll
        for (int j = 0; j < 4; ++j) pm[j] = fmaxf(pm[j], __shfl_xor(pm[j], off, 64));
      f32x4 sum = zero4;
#pragma unroll
      for (int nt = 0; nt < 4; ++nt)
#pragma unroll
        for (int j = 0; j < 4; ++j) {
          const float e = __expf(s[mt][nt][j] - pm[j]);
          s[mt][nt][j] = e;
          sum[j] += e;
        }
#pragma unroll
      for (int off = 1; off <= 8; off <<= 1)
#pragma unroll
        for (int j = 0; j < 4; ++j) sum[j] += __shfl_xor(sum[j], off, 64);
#pragma unroll
      for (int j = 0; j < 4; ++j) pm[j] = 1.f / sum[j];
#pragma unroll
      for (int nt = 0; nt < 4; ++nt)
#pragma unroll
        for (int j = 0; j < 4; ++j) s[mt][nt][j] *= pm[j];
    }
  }
  __syncthreads();  // B2: all qs/ks reads done -> ps overlay safe

  // prefetch proj B-fragments (independent global loads)
  bf16x8 wpb[2][4];
#pragma unroll
  for (int n = 0; n < 2; ++n)
#pragma unroll
    for (int kk = 0; kk < 4; ++kk)
      wpb[n][kk] = *(const bf16x8*)(wp + (size_t)(((w * 2 + n) * 4 + kk) * 64 + lane) * 8);

  // ---- phase 3b: P -> LDS, PV ----
  f32x4 o[4][2];
  {
    const int h = w;
    __bf16* psh = ps + h * QR * PS;
    const __bf16* vth = vt + h * 32 * VS;
#pragma unroll
    for (int mt = 0; mt < 4; ++mt)
#pragma unroll
      for (int nt = 0; nt < 4; ++nt)
#pragma unroll
        for (int j = 0; j < 4; ++j) {
          const int r = mt * 16 + lg * 4 + j;
          if (r < kN) psh[r * PS + nt * 16 + lm] = (__bf16)s[mt][nt][j];
        }
#pragma unroll
    for (int mt = 0; mt < 4; ++mt)
#pragma unroll
      for (int n2 = 0; n2 < 2; ++n2) o[mt][n2] = zero4;
#pragma unroll
    for (int kk = 0; kk < 2; ++kk) {
      bf16x8 vf[2];
#pragma unroll
      for (int n2 = 0; n2 < 2; ++n2)
        vf[n2] = *(const bf16x8*)(vth + (n2 * 16 + lm) * VS + kk * 32 + lg * 8);
#pragma unroll
      for (int mt = 0; mt < 4; ++mt) {
        bf16x8 pf = *(const bf16x8*)(psh + (mt * 16 + lm) * PS + kk * 32 + lg * 8);
#pragma unroll
        for (int n2 = 0; n2 < 2; ++n2) o[mt][n2] = MFMA16(pf, vf[n2], o[mt][n2]);
      }
    }
  }
  __syncthreads();  // B3: PV LDS reads done -> ob overlay safe

#pragma unroll
  for (int mt = 0; mt < 4; ++mt)
#pragma unroll
    for (int n2 = 0; n2 < 2; ++n2)
#pragma unroll
      for (int j = 0; j < 4; ++j) {
        const int r = mt * 16 + lg * 4 + j;
        if (r < kN) ob[r * OBS + w * 32 + n2 * 16 + lm] = (__bf16)o[mt][n2][j];
      }
  __syncthreads();  // B4: ob ready

  // ---- phase 4: proj GEMM + bias -> out (f32) ----
  {
    bf16x8 paf[4][4];
#pragma unroll
    for (int mt = 0; mt < 4; ++mt)
#pragma unroll
      for (int kk = 0; kk < 4; ++kk)
        paf[mt][kk] = *(const bf16x8*)(ob + (mt * 16 + lm) * OBS + kk * 32 + lg * 8);

    float* op = out + (size_t)b * (kN * kC);
#pragma unroll
    for (int n = 0; n < 2; ++n) {
      f32x4 acc[4];
#pragma unroll
      for (int mt = 0; mt < 4; ++mt) acc[mt] = zero4;
#pragma unroll
      for (int kk = 0; kk < 4; ++kk)
#pragma unroll
        for (int mt = 0; mt < 4; ++mt)
          acc[mt] = MFMA16(paf[mt][kk], wpb[n][kk], acc[mt]);
      const int cc = (w * 2 + n) * 16 + lm;
      const float pb = proj_b[cc];
#pragma unroll
      for (int mt = 0; mt < 4; ++mt)
#pragma unroll
        for (int j = 0; j < 4; ++j) {
          const int r = mt * 16 + lg * 4 + j;
          if (r < kN) op[r * kC + cc] = acc[mt][j] + pb;
        }
    }
  }
}

// ---------------------------------------------------------------------------
extern "C" void kernel_launch(void* const* d_in, const int* in_sizes, int n_in,
                              void* d_out, int out_size, void* d_ws, size_t ws_size,
                              hipStream_t stream) {
  const float* x          = (const float*)d_in[0];
  const float* mask       = (const float*)d_in[1];
  const float* qkv_w      = (const float*)d_in[2];
  const float* qkv_b      = (const float*)d_in[3];
  const float* proj_w     = (const float*)d_in[4];
  const float* proj_b     = (const float*)d_in[5];
  const float* bias_table = (const float*)d_in[6];
  const int*   rel        = (const int*)d_in[7];

  char* ws = (char*)d_ws;
  __bf16* wq   = (__bf16*)(ws + WQ_OFF);
  __bf16* wp   = (__bf16*)(ws + WP_OFF);
  float* biasp = (float*)(ws + BP_OFF);
  float* cm    = (float*)(ws + CM_OFF);

  const bool use_cm = (ws_size >= WS_NEED);
  const int prep_blocks = use_cm ? (96 + 4096) : 96;
  prep_kernel<<<prep_blocks, 256, 0, stream>>>(qkv_w, proj_w, bias_table, rel,
                                               mask, wq, wp, biasp, cm);
  if (use_cm)
    wattn_fused<true><<<kB, 256, 0, stream>>>(x, mask, qkv_b, proj_b, wq, wp,
                                              biasp, cm, (float*)d_out);
  else
    wattn_fused<false><<<kB, 256, 0, stream>>>(x, mask, qkv_b, proj_b, wq, wp,
                                               biasp, cm, (float*)d_out);
}

// Round 4
// 152.268 us; speedup vs baseline: 1.0052x; 1.0052x over previous
//
#include <hip/hip_runtime.h>
#include <hip/hip_bf16.h>

typedef __bf16 bf16x8 __attribute__((ext_vector_type(8)));
typedef __bf16 bf16x4 __attribute__((ext_vector_type(4)));
typedef float f32x4 __attribute__((ext_vector_type(4)));

#define MFMA16(a, b, c) __builtin_amdgcn_mfma_f32_16x16x32_bf16((a), (b), (c), 0, 0, 0)

constexpr int kB = 4096, kN = 49, kC = 128;
constexpr float kScale = 0.17677669529663687f;  // 32^-0.5

// workspace layout (bytes)
constexpr size_t WQ_OFF = 0;        // qkv_w packed bf16: [24][4][64][8] = 98304 B
constexpr size_t WP_OFF = 98304;    // proj_w packed bf16: [8][4][64][8] = 32768 B
constexpr size_t BP_OFF = 131072;   // bias f32 [4][64r][64cc] (fallback) = 65536 B
constexpr size_t CM_OFF = 196608;   // combined bias+mask f32 [64][4][64 tok][64 key] = 4 MiB
constexpr size_t CM_BYTES = (size_t)64 * 4 * 64 * 64 * 4;
constexpr size_t WS_NEED = CM_OFF + CM_BYTES;

// ---------------------------------------------------------------------------
// prep: repack weights bf16 fragment-linear; gather bias; build bias+mask table
// wq/wp store W[k][c] at [c-tile][kk][lane(c=lm,k=lg*8+i)][i] — serves as BOTH
// B-frag (C = x·W) and A-frag (C = W^T·x^T) layout.
// ---------------------------------------------------------------------------
__global__ void prep_kernel(const float* __restrict__ qkv_w,
                            const float* __restrict__ proj_w,
                            const float* __restrict__ bias_table,
                            const int* __restrict__ rel_raw,
                            const float* __restrict__ maskp,
                            __bf16* __restrict__ wq, __bf16* __restrict__ wp,
                            float* __restrict__ biasp, float* __restrict__ cm) {
  const int blk = blockIdx.x, t = threadIdx.x;
  // int64-vs-int32 sniff: rel[0]=84 -> int64 word1 is 0; int32 word1 = 83
  const bool is64 = (rel_raw[1] == 0);
  if (blk < 24) {  // qkv_w pack
    const int kk = t >> 6, lane = t & 63;
    const int k0 = kk * 32 + ((lane >> 4) << 3);
    const int c  = blk * 16 + (lane & 15);
#pragma unroll
    for (int i = 0; i < 8; ++i)
      wq[((blk * 4 + kk) * 64 + lane) * 8 + i] = (__bf16)qkv_w[(k0 + i) * 384 + c];
  } else if (blk < 32) {  // proj_w pack
    const int nt = blk - 24;
    const int kk = t >> 6, lane = t & 63;
    const int k0 = kk * 32 + ((lane >> 4) << 3);
    const int c  = nt * 16 + (lane & 15);
#pragma unroll
    for (int i = 0; i < 8; ++i)
      wp[((nt * 4 + kk) * 64 + lane) * 8 + i] = (__bf16)proj_w[(k0 + i) * 128 + c];
  } else if (blk < 96) {  // biasp [h][r][cc] fallback table
    const int e = (blk - 32) * 256 + t;
    const int h = e >> 12, i = (e >> 6) & 63, j = e & 63;
    float v = 0.f;
    if (i < kN && j < kN) {
      const int flat = i * kN + j;
      const int idx = is64 ? rel_raw[2 * flat] : rel_raw[flat];
      v = bias_table[idx * 4 + h];
    }
    biasp[(h * 64 + i) * 64 + j] = v;
  } else {  // combined table cm[wm][h][tok r][key cc]
    const int e = (blk - 96) * 256 + t;  // 0..2^20-1
    const int wm = e >> 14, h = (e >> 12) & 3, r = (e >> 6) & 63, cc = e & 63;
    float v;
    if (cc >= kN) v = -1e30f;          // padded keys -> -inf
    else if (r >= kN) v = 0.f;         // padded tokens: rows discarded later
    else {
      const int flat = r * kN + cc;
      const int idx = is64 ? rel_raw[2 * flat] : rel_raw[flat];
      v = bias_table[idx * 4 + h] + maskp[wm * (kN * kN) + flat];
    }
    cm[(((size_t)(wm * 4 + h)) << 12) + (r << 6) + cc] = v;
  }
}

// ---------------------------------------------------------------------------
// lg-group redistribution: source tiles hold M[idx = src16*16 + lg*4 + j] at
// (lane lm) packed as uint2 (j0j1, j2j3); produce frag lane-layout
// M[idx = lg*8 + i], i=0..7 (bf16x8). p0 = idx 0..15 tile, p1 = idx 16..31.
// ---------------------------------------------------------------------------
__device__ __forceinline__ uint2 pack4(f32x4 v) {
  bf16x4 h;
  h[0] = (__bf16)v[0]; h[1] = (__bf16)v[1]; h[2] = (__bf16)v[2]; h[3] = (__bf16)v[3];
  return *(uint2*)&h;
}

__device__ __forceinline__ bf16x8 redis(uint2 p0, uint2 p1, int lane) {
  const int base = (lane & 15) + ((lane >> 4) & 1) * 32;
  const bool hi = lane >= 32;  // lg>=2 -> take from p1 (idx 16..31)
  unsigned a, b;
  uint4 w;
  a = __shfl((int)p0.x, base);      b = __shfl((int)p1.x, base);      w.x = hi ? b : a;
  a = __shfl((int)p0.y, base);      b = __shfl((int)p1.y, base);      w.y = hi ? b : a;
  a = __shfl((int)p0.x, base + 16); b = __shfl((int)p1.x, base + 16); w.z = hi ? b : a;
  a = __shfl((int)p0.y, base + 16); b = __shfl((int)p1.y, base + 16); w.w = hi ? b : a;
  return *(bf16x8*)&w;
}

// ---------------------------------------------------------------------------
// fused window attention: 1 block = 1 window, 4 waves = 4 heads.
// Register-resident attention (Q^T/K^T/V computed per-head, S^T orientation),
// LDS only for cross-head proj staging (17.4 KB), single barrier.
// ---------------------------------------------------------------------------
template <bool USE_CM>
__global__ __launch_bounds__(256, 3)
void wattn_fused(const float* __restrict__ x, const float* __restrict__ mask,
                 const float* __restrict__ qkv_b, const float* __restrict__ proj_b,
                 const __bf16* __restrict__ wq, const __bf16* __restrict__ wp,
                 const float* __restrict__ biasp, const float* __restrict__ cm,
                 float* __restrict__ out) {
  constexpr int OBS = 136;
  __shared__ __align__(16) __bf16 ob[64 * OBS];  // 17408 B

  const int tid = threadIdx.x;
  const int w = tid >> 6, lane = tid & 63, lg = lane >> 4, lm = lane & 15;
  const int b = blockIdx.x;
  const f32x4 zero4 = {0.f, 0.f, 0.f, 0.f};

  // ---- x fragments: af[tt][kk] = x[tok=tt*16+lm][in=kk*32+lg*8+i] ----
  bf16x8 af[4][4];
  {
    const float* xp = x + (size_t)b * (kN * kC);
#pragma unroll
    for (int tt = 0; tt < 4; ++tt) {
      const int r = tt * 16 + lm;
      const float* rp = xp + (r < kN ? r : 0) * kC;
      const bool ok = r < kN;
#pragma unroll
      for (int kk = 0; kk < 4; ++kk) {
        f32x4 lo = *(const f32x4*)(rp + kk * 32 + lg * 8);
        f32x4 hi = *(const f32x4*)(rp + kk * 32 + lg * 8 + 4);
        bf16x8 tf;
#pragma unroll
        for (int i2 = 0; i2 < 4; ++i2) {
          tf[i2]     = (__bf16)(ok ? lo[i2] : 0.f);
          tf[4 + i2] = (__bf16)(ok ? hi[i2] : 0.f);
        }
        af[tt][kk] = tf;
      }
    }
  }

  bf16x8 qf[4], kf[4], vf[2][2];

  // ---- Q^T = Wq_head^T x^T  (acc: [dim=dt*16+lg*4+j][tok=lm]) ----
  {
    uint2 pq[2][4];
#pragma unroll
    for (int dt = 0; dt < 2; ++dt) {
      const int ct = 2 * w + dt;
      bf16x8 wf[4];
#pragma unroll
      for (int kk = 0; kk < 4; ++kk)
        wf[kk] = *(const bf16x8*)(wq + ((size_t)(ct * 4 + kk) * 64 + lane) * 8);
      f32x4 qb4 = *(const f32x4*)(qkv_b + w * 32 + dt * 16 + lg * 4);
#pragma unroll
      for (int tt = 0; tt < 4; ++tt) {
        f32x4 acc = zero4;
#pragma unroll
        for (int kk = 0; kk < 4; ++kk) acc = MFMA16(wf[kk], af[tt][kk], acc);
#pragma unroll
        for (int j = 0; j < 4; ++j) acc[j] = (acc[j] + qb4[j]) * kScale;
        pq[dt][tt] = pack4(acc);
      }
    }
#pragma unroll
    for (int tt = 0; tt < 4; ++tt) qf[tt] = redis(pq[0][tt], pq[1][tt], lane);
  }

  // ---- K^T ----
  {
    uint2 pk[2][4];
#pragma unroll
    for (int dt = 0; dt < 2; ++dt) {
      const int ct = 8 + 2 * w + dt;
      bf16x8 wf[4];
#pragma unroll
      for (int kk = 0; kk < 4; ++kk)
        wf[kk] = *(const bf16x8*)(wq + ((size_t)(ct * 4 + kk) * 64 + lane) * 8);
      f32x4 kb4 = *(const f32x4*)(qkv_b + 128 + w * 32 + dt * 16 + lg * 4);
#pragma unroll
      for (int tt = 0; tt < 4; ++tt) {
        f32x4 acc = zero4;
#pragma unroll
        for (int kk = 0; kk < 4; ++kk) acc = MFMA16(wf[kk], af[tt][kk], acc);
#pragma unroll
        for (int j = 0; j < 4; ++j) acc[j] += kb4[j];
        pk[dt][tt] = pack4(acc);
      }
    }
#pragma unroll
    for (int kt = 0; kt < 4; ++kt) kf[kt] = redis(pk[0][kt], pk[1][kt], lane);
  }

  // ---- V = x Wv (acc: [tok=mt*16+lg*4+j][d=dt*16+lm]) ----
  {
    uint2 pv[4][2];
#pragma unroll
    for (int dt = 0; dt < 2; ++dt) {
      const int ct = 16 + 2 * w + dt;
      bf16x8 wf[4];
#pragma unroll
      for (int kk = 0; kk < 4; ++kk)
        wf[kk] = *(const bf16x8*)(wq + ((size_t)(ct * 4 + kk) * 64 + lane) * 8);
      const float vb = qkv_b[256 + w * 32 + dt * 16 + lm];
#pragma unroll
      for (int mt = 0; mt < 4; ++mt) {
        f32x4 acc = zero4;
#pragma unroll
        for (int kk = 0; kk < 4; ++kk) acc = MFMA16(af[mt][kk], wf[kk], acc);
#pragma unroll
        for (int j = 0; j < 4; ++j) acc[j] += vb;
        pv[mt][dt] = pack4(acc);
      }
    }
#pragma unroll
    for (int k2 = 0; k2 < 2; ++k2)
#pragma unroll
      for (int dt = 0; dt < 2; ++dt)
        vf[k2][dt] = redis(pv[k2 * 2][dt], pv[k2 * 2 + 1][dt], lane);
  }

  // ---- attention per token-tile: S^T = K·Q^T, softmax over keys, PV ----
  const float* cmp = cm + (((size_t)((b & 63) * 4 + w)) << 12);
  const float* bpp = biasp + w * 4096;
  const float* mkp = mask + (size_t)(b & 63) * (kN * kN);

#pragma unroll
  for (int tt = 0; tt < 4; ++tt) {
    f32x4 st[4];
#pragma unroll
    for (int kt = 0; kt < 4; ++kt) st[kt] = MFMA16(kf[kt], qf[tt], zero4);
    const int tok = tt * 16 + lm;
    if (USE_CM) {
#pragma unroll
      for (int kt = 0; kt < 4; ++kt) {
        f32x4 bm = *(const f32x4*)(cmp + (tok << 6) + kt * 16 + lg * 4);
#pragma unroll
        for (int j = 0; j < 4; ++j) st[kt][j] += bm[j];
      }
    } else {
#pragma unroll
      for (int kt = 0; kt < 4; ++kt)
#pragma unroll
        for (int j = 0; j < 4; ++j) {
          const int key = kt * 16 + lg * 4 + j;
          float v = st[kt][j];
          if (key >= kN) v = -1e30f;
          else if (tok < kN) v += bpp[(tok << 6) + key] + mkp[tok * kN + key];
          st[kt][j] = v;
        }
    }
    // softmax over keys (keys live on (kt, lg, j); token on lm)
    float m = -3e38f;
#pragma unroll
    for (int kt = 0; kt < 4; ++kt)
#pragma unroll
      for (int j = 0; j < 4; ++j) m = fmaxf(m, st[kt][j]);
    m = fmaxf(m, __shfl_xor(m, 16));
    m = fmaxf(m, __shfl_xor(m, 32));
    float sum = 0.f;
#pragma unroll
    for (int kt = 0; kt < 4; ++kt)
#pragma unroll
      for (int j = 0; j < 4; ++j) {
        const float e = __expf(st[kt][j] - m);
        st[kt][j] = e;
        sum += e;
      }
    sum += __shfl_xor(sum, 16);
    sum += __shfl_xor(sum, 32);
    const float rs = 1.f / sum;
    uint2 pst[4];
#pragma unroll
    for (int kt = 0; kt < 4; ++kt) {
      f32x4 t;
#pragma unroll
      for (int j = 0; j < 4; ++j) t[j] = st[kt][j] * rs;
      pst[kt] = pack4(t);
    }
    bf16x8 pa0 = redis(pst[0], pst[1], lane);
    bf16x8 pa1 = redis(pst[2], pst[3], lane);
#pragma unroll
    for (int dt = 0; dt < 2; ++dt) {
      f32x4 o = MFMA16(pa0, vf[0][dt], zero4);
      o = MFMA16(pa1, vf[1][dt], o);
#pragma unroll
      for (int j = 0; j < 4; ++j) {
        const int tk = tt * 16 + lg * 4 + j;
        if (tk < kN) ob[tk * OBS + w * 32 + dt * 16 + lm] = (__bf16)o[j];
      }
    }
  }

  // prefetch proj B-fragments while ob settles
  bf16x8 wpb[2][4];
#pragma unroll
  for (int n = 0; n < 2; ++n)
#pragma unroll
    for (int kk = 0; kk < 4; ++kk)
      wpb[n][kk] = *(const bf16x8*)(wp + (size_t)(((w * 2 + n) * 4 + kk) * 64 + lane) * 8);

  __syncthreads();  // ob ready (only barrier in the kernel)

  // ---- proj GEMM [64x128]@[128x128] + bias -> out (f32) ----
  {
    bf16x8 paf[4][4];
#pragma unroll
    for (int mt = 0; mt < 4; ++mt)
#pragma unroll
      for (int kk = 0; kk < 4; ++kk)
        paf[mt][kk] = *(const bf16x8*)(ob + (mt * 16 + lm) * OBS + kk * 32 + lg * 8);

    float* op = out + (size_t)b * (kN * kC);
#pragma unroll
    for (int n = 0; n < 2; ++n) {
      f32x4 acc[4];
#pragma unroll
      for (int mt = 0; mt < 4; ++mt) acc[mt] = zero4;
#pragma unroll
      for (int kk = 0; kk < 4; ++kk)
#pragma unroll
        for (int mt = 0; mt < 4; ++mt)
          acc[mt] = MFMA16(paf[mt][kk], wpb[n][kk], acc[mt]);
      const int cc = (w * 2 + n) * 16 + lm;
      const float pb = proj_b[cc];
#pragma unroll
      for (int mt = 0; mt < 4; ++mt)
#pragma unroll
        for (int j = 0; j < 4; ++j) {
          const int r = mt * 16 + lg * 4 + j;
          if (r < kN) op[r * kC + cc] = acc[mt][j] + pb;
        }
    }
  }
}

// ---------------------------------------------------------------------------
extern "C" void kernel_launch(void* const* d_in, const int* in_sizes, int n_in,
                              void* d_out, int out_size, void* d_ws, size_t ws_size,
                              hipStream_t stream) {
  const float* x          = (const float*)d_in[0];
  const float* mask       = (const float*)d_in[1];
  const float* qkv_w      = (const float*)d_in[2];
  const float* qkv_b      = (const float*)d_in[3];
  const float* proj_w     = (const float*)d_in[4];
  const float* proj_b     = (const float*)d_in[5];
  const float* bias_table = (const float*)d_in[6];
  const int*   rel        = (const int*)d_in[7];

  char* ws = (char*)d_ws;
  __bf16* wq   = (__bf16*)(ws + WQ_OFF);
  __bf16* wp   = (__bf16*)(ws + WP_OFF);
  float* biasp = (float*)(ws + BP_OFF);
  float* cm    = (float*)(ws + CM_OFF);

  const bool use_cm = (ws_size >= WS_NEED);
  const int prep_blocks = use_cm ? (96 + 4096) : 96;
  prep_kernel<<<prep_blocks, 256, 0, stream>>>(qkv_w, proj_w, bias_table, rel,
                                               mask, wq, wp, biasp, cm);
  if (use_cm)
    wattn_fused<true><<<kB, 256, 0, stream>>>(x, mask, qkv_b, proj_b, wq, wp,
                                              biasp, cm, (float*)d_out);
  else
    wattn_fused<false><<<kB, 256, 0, stream>>>(x, mask, qkv_b, proj_b, wq, wp,
                                               biasp, cm, (float*)d_out);
}

// Round 5
// 109.552 us; speedup vs baseline: 1.3971x; 1.3899x over previous
//
#include <hip/hip_runtime.h>
#include <hip/hip_bf16.h>

typedef __bf16 bf16x8 __attribute__((ext_vector_type(8)));
typedef __bf16 bf16x4 __attribute__((ext_vector_type(4)));
typedef float f32x4 __attribute__((ext_vector_type(4)));

#define MFMA16(a, b, c) __builtin_amdgcn_mfma_f32_16x16x32_bf16((a), (b), (c), 0, 0, 0)

constexpr int kB = 4096, kN = 49, kC = 128;
constexpr float kScale = 0.17677669529663687f;  // 32^-0.5

// workspace layout (bytes)
constexpr size_t WQ_OFF = 0;        // qkv_w packed bf16: [24][4][64][8] = 98304 B
constexpr size_t WP_OFF = 98304;    // proj_w packed bf16: [8][4][64][8] = 32768 B
constexpr size_t BP_OFF = 131072;   // bias f32 [4][64 tok][64 key] (-1e30 at key>=49) = 64 KB
constexpr size_t MF_OFF = 196608;   // mask-nonzero flags: 8 ints

// ---------------------------------------------------------------------------
// prep: pack weights bf16 fragment-linear (serves both A- and B-frag roles);
// build per-head bias table with key-mask folded in; reduce mask to 8 flags.
// ---------------------------------------------------------------------------
__global__ void prep_kernel(const float* __restrict__ qkv_w,
                            const float* __restrict__ proj_w,
                            const float* __restrict__ bias_table,
                            const int* __restrict__ rel_raw,
                            const float* __restrict__ maskp,
                            __bf16* __restrict__ wq, __bf16* __restrict__ wp,
                            float* __restrict__ biasp, int* __restrict__ mf) {
  const int blk = blockIdx.x, t = threadIdx.x;
  // int64-vs-int32 sniff: rel[0]=84 -> int64 word1 is 0; int32 word1 = 83
  const bool is64 = (rel_raw[1] == 0);
  if (blk < 24) {  // qkv_w pack
    const int kk = t >> 6, lane = t & 63;
    const int k0 = kk * 32 + ((lane >> 4) << 3);
    const int c  = blk * 16 + (lane & 15);
#pragma unroll
    for (int i = 0; i < 8; ++i)
      wq[((blk * 4 + kk) * 64 + lane) * 8 + i] = (__bf16)qkv_w[(k0 + i) * 384 + c];
  } else if (blk < 32) {  // proj_w pack
    const int nt = blk - 24;
    const int kk = t >> 6, lane = t & 63;
    const int k0 = kk * 32 + ((lane >> 4) << 3);
    const int c  = nt * 16 + (lane & 15);
#pragma unroll
    for (int i = 0; i < 8; ++i)
      wp[((nt * 4 + kk) * 64 + lane) * 8 + i] = (__bf16)proj_w[(k0 + i) * 128 + c];
  } else if (blk < 96) {  // biasp [h][tok64][key64], key>=49 -> -1e30
    const int e = (blk - 32) * 256 + t;
    const int h = e >> 12, tok = (e >> 6) & 63, key = e & 63;
    float v;
    if (key >= kN) v = -1e30f;
    else if (tok >= kN) v = 0.f;
    else {
      const int flat = tok * kN + key;
      const int idx = is64 ? rel_raw[2 * flat] : rel_raw[flat];
      v = bias_table[idx * 4 + h];
    }
    biasp[(h * 64 + tok) * 64 + key] = v;
  } else {  // blk 96..103: mask nonzero flag (64*49*49 = 153664 elems)
    const int base = (blk - 96) * 19208;
    int any = 0;
    for (int e = base + t; e < base + 19208; e += 256)
      any |= (__float_as_uint(maskp[e]) != 0u) ? 1 : 0;
    const int blkany = __syncthreads_or(any);
    if (t == 0) mf[blk - 96] = blkany;
  }
}

// ---------------------------------------------------------------------------
// lg-group redistribution (verified R4): tiles hold M[idx = src16*16 + lg*4+j]
// at lane lm, packed as uint2; produce frag layout M[idx = lg*8 + i] (bf16x8).
// ---------------------------------------------------------------------------
__device__ __forceinline__ uint2 pack4(f32x4 v) {
  bf16x4 h;
  h[0] = (__bf16)v[0]; h[1] = (__bf16)v[1]; h[2] = (__bf16)v[2]; h[3] = (__bf16)v[3];
  return *(uint2*)&h;
}

__device__ __forceinline__ bf16x8 redis(uint2 p0, uint2 p1, int lane) {
  const int base = (lane & 15) + ((lane >> 4) & 1) * 32;
  const bool hi = lane >= 32;
  unsigned a, b;
  uint4 w;
  a = __shfl((int)p0.x, base);      b = __shfl((int)p1.x, base);      w.x = hi ? b : a;
  a = __shfl((int)p0.y, base);      b = __shfl((int)p1.y, base);      w.y = hi ? b : a;
  a = __shfl((int)p0.x, base + 16); b = __shfl((int)p1.x, base + 16); w.z = hi ? b : a;
  a = __shfl((int)p0.y, base + 16); b = __shfl((int)p1.y, base + 16); w.w = hi ? b : a;
  return *(bf16x8*)&w;
}

// ---------------------------------------------------------------------------
// fused window attention: 1 block = 1 window, 4 waves = 4 heads.
// x staged once in LDS (A-frags read transiently), attention register-resident,
// 2 barriers. Rows 49-63 replicate row 48; -1e30 bias kills padded keys.
// ---------------------------------------------------------------------------
__global__ __launch_bounds__(256, 4)
void wattn_fused(const float* __restrict__ x, const float* __restrict__ qkv_b,
                 const float* __restrict__ proj_b,
                 const __bf16* __restrict__ wq, const __bf16* __restrict__ wp,
                 const float* __restrict__ biasp, const float* __restrict__ mask,
                 const int* __restrict__ mf, float* __restrict__ out) {
  constexpr int XS = 136, OBS = 136;
  __shared__ __align__(16) __bf16 xb[64 * XS];  // 17408 B
  __shared__ __align__(16) __bf16 ob[64 * OBS]; // 17408 B

  const int tid = threadIdx.x;
  const int w = tid >> 6, lane = tid & 63, lg = lane >> 4, lm = lane & 15;
  const int b = blockIdx.x;
  const f32x4 zero4 = {0.f, 0.f, 0.f, 0.f};

  const bool hasMask =
      (mf[0] | mf[1] | mf[2] | mf[3] | mf[4] | mf[5] | mf[6] | mf[7]) != 0;

  // ---- stage x -> xb bf16 (rows 49-63 = row 48 replica) ----
  {
    const float* xp = x + (size_t)b * (kN * kC);
#pragma unroll
    for (int i = 0; i < 8; ++i) {
      const int it = tid + i * 256;
      const int row = it >> 5, col = (it & 31) << 2;
      const int sr = row < kN ? row : (kN - 1);
      f32x4 v = *(const f32x4*)(xp + sr * kC + col);
      bf16x4 h;
      h[0] = (__bf16)v[0]; h[1] = (__bf16)v[1]; h[2] = (__bf16)v[2]; h[3] = (__bf16)v[3];
      *(bf16x4*)(xb + row * XS + col) = h;
    }
  }
  __syncthreads();  // B1: xb ready

#define LDAF(tt, kk) (*(const bf16x8*)(xb + ((tt) * 16 + lm) * XS + (kk) * 32 + lg * 8))

  bf16x8 qf[4], kf[4], vf[2][2];

  // ---- Q^T = Wq_h^T x^T  (acc: [dim=dt*16+lg*4+j][tok=lm]) ----
  {
    uint2 pq[2][4];
#pragma unroll
    for (int dt = 0; dt < 2; ++dt) {
      const int ct = 2 * w + dt;
      bf16x8 wf[4];
#pragma unroll
      for (int kk = 0; kk < 4; ++kk)
        wf[kk] = *(const bf16x8*)(wq + ((size_t)(ct * 4 + kk) * 64 + lane) * 8);
      f32x4 qb4 = *(const f32x4*)(qkv_b + w * 32 + dt * 16 + lg * 4);
#pragma unroll
      for (int tt = 0; tt < 4; ++tt) {
        f32x4 acc = zero4;
        __builtin_amdgcn_s_setprio(1);
#pragma unroll
        for (int kk = 0; kk < 4; ++kk) acc = MFMA16(wf[kk], LDAF(tt, kk), acc);
        __builtin_amdgcn_s_setprio(0);
#pragma unroll
        for (int j = 0; j < 4; ++j) acc[j] = (acc[j] + qb4[j]) * kScale;
        pq[dt][tt] = pack4(acc);
      }
    }
#pragma unroll
    for (int tt = 0; tt < 4; ++tt) qf[tt] = redis(pq[0][tt], pq[1][tt], lane);
  }

  // ---- K^T ----
  {
    uint2 pk[2][4];
#pragma unroll
    for (int dt = 0; dt < 2; ++dt) {
      const int ct = 8 + 2 * w + dt;
      bf16x8 wf[4];
#pragma unroll
      for (int kk = 0; kk < 4; ++kk)
        wf[kk] = *(const bf16x8*)(wq + ((size_t)(ct * 4 + kk) * 64 + lane) * 8);
      f32x4 kb4 = *(const f32x4*)(qkv_b + 128 + w * 32 + dt * 16 + lg * 4);
#pragma unroll
      for (int tt = 0; tt < 4; ++tt) {
        f32x4 acc = zero4;
        __builtin_amdgcn_s_setprio(1);
#pragma unroll
        for (int kk = 0; kk < 4; ++kk) acc = MFMA16(wf[kk], LDAF(tt, kk), acc);
        __builtin_amdgcn_s_setprio(0);
#pragma unroll
        for (int j = 0; j < 4; ++j) acc[j] += kb4[j];
        pk[dt][tt] = pack4(acc);
      }
    }
#pragma unroll
    for (int kt = 0; kt < 4; ++kt) kf[kt] = redis(pk[0][kt], pk[1][kt], lane);
  }

  // ---- V = x Wv (acc: [tok=mt*16+lg*4+j][d=dt*16+lm]) ----
  {
    uint2 pv[4][2];
#pragma unroll
    for (int dt = 0; dt < 2; ++dt) {
      const int ct = 16 + 2 * w + dt;
      bf16x8 wf[4];
#pragma unroll
      for (int kk = 0; kk < 4; ++kk)
        wf[kk] = *(const bf16x8*)(wq + ((size_t)(ct * 4 + kk) * 64 + lane) * 8);
      const float vb = qkv_b[256 + w * 32 + dt * 16 + lm];
#pragma unroll
      for (int mt = 0; mt < 4; ++mt) {
        f32x4 acc = zero4;
        __builtin_amdgcn_s_setprio(1);
#pragma unroll
        for (int kk = 0; kk < 4; ++kk) acc = MFMA16(LDAF(mt, kk), wf[kk], acc);
        __builtin_amdgcn_s_setprio(0);
#pragma unroll
        for (int j = 0; j < 4; ++j) acc[j] += vb;
        pv[mt][dt] = pack4(acc);
      }
    }
#pragma unroll
    for (int k2 = 0; k2 < 2; ++k2)
#pragma unroll
      for (int dt = 0; dt < 2; ++dt)
        vf[k2][dt] = redis(pv[k2 * 2][dt], pv[k2 * 2 + 1][dt], lane);
  }

  // ---- attention: S^T = K·Q^T (+bias table incl. key mask), softmax, PV ----
  const float* bpp = biasp + w * 4096;
  const float* mkp = mask + (size_t)(b & 63) * (kN * kN);

#pragma unroll
  for (int tt = 0; tt < 4; ++tt) {
    f32x4 st[4];
    __builtin_amdgcn_s_setprio(1);
#pragma unroll
    for (int kt = 0; kt < 4; ++kt) st[kt] = MFMA16(kf[kt], qf[tt], zero4);
    __builtin_amdgcn_s_setprio(0);
    const int tok = tt * 16 + lm;
#pragma unroll
    for (int kt = 0; kt < 4; ++kt) {
      f32x4 bm = *(const f32x4*)(bpp + (tok << 6) + kt * 16 + lg * 4);
#pragma unroll
      for (int j = 0; j < 4; ++j) st[kt][j] += bm[j];
    }
    if (hasMask) {
      const int tok2 = tok < kN ? tok : (kN - 1);
#pragma unroll
      for (int kt = 0; kt < 4; ++kt)
#pragma unroll
        for (int j = 0; j < 4; ++j) {
          const int key = kt * 16 + lg * 4 + j;
          const int key2 = key < kN ? key : (kN - 1);
          st[kt][j] += mkp[tok2 * kN + key2];
        }
    }
    // softmax over keys (keys on (kt,lg,j); token on lm)
    float m = -3e38f;
#pragma unroll
    for (int kt = 0; kt < 4; ++kt)
#pragma unroll
      for (int j = 0; j < 4; ++j) m = fmaxf(m, st[kt][j]);
    m = fmaxf(m, __shfl_xor(m, 16));
    m = fmaxf(m, __shfl_xor(m, 32));
    float sum = 0.f;
#pragma unroll
    for (int kt = 0; kt < 4; ++kt)
#pragma unroll
      for (int j = 0; j < 4; ++j) {
        const float e = __expf(st[kt][j] - m);
        st[kt][j] = e;
        sum += e;
      }
    sum += __shfl_xor(sum, 16);
    sum += __shfl_xor(sum, 32);
    const float rs = 1.f / sum;
    uint2 pst[4];
#pragma unroll
    for (int kt = 0; kt < 4; ++kt) {
      f32x4 t;
#pragma unroll
      for (int j = 0; j < 4; ++j) t[j] = st[kt][j] * rs;
      pst[kt] = pack4(t);
    }
    bf16x8 pa0 = redis(pst[0], pst[1], lane);
    bf16x8 pa1 = redis(pst[2], pst[3], lane);
#pragma unroll
    for (int dt = 0; dt < 2; ++dt) {
      f32x4 o = MFMA16(pa0, vf[0][dt], zero4);
      o = MFMA16(pa1, vf[1][dt], o);
#pragma unroll
      for (int j = 0; j < 4; ++j)
        ob[(tt * 16 + lg * 4 + j) * OBS + w * 32 + dt * 16 + lm] = (__bf16)o[j];
    }
  }
  __syncthreads();  // B2: ob ready

  // ---- proj GEMM [64x128]@[128x128] + bias -> out (f32) ----
  {
    float* op = out + (size_t)b * (kN * kC);
#pragma unroll
    for (int n = 0; n < 2; ++n) {
      bf16x8 wpb[4];
#pragma unroll
      for (int kk = 0; kk < 4; ++kk)
        wpb[kk] = *(const bf16x8*)(wp + (size_t)(((w * 2 + n) * 4 + kk) * 64 + lane) * 8);
      f32x4 acc[4];
#pragma unroll
      for (int mt = 0; mt < 4; ++mt) acc[mt] = zero4;
#pragma unroll
      for (int kk = 0; kk < 4; ++kk) {
        __builtin_amdgcn_s_setprio(1);
#pragma unroll
        for (int mt = 0; mt < 4; ++mt)
          acc[mt] = MFMA16(*(const bf16x8*)(ob + (mt * 16 + lm) * OBS + kk * 32 + lg * 8),
                           wpb[kk], acc[mt]);
        __builtin_amdgcn_s_setprio(0);
      }
      const int cc = (w * 2 + n) * 16 + lm;
      const float pb = proj_b[cc];
#pragma unroll
      for (int mt = 0; mt < 4; ++mt)
#pragma unroll
        for (int j = 0; j < 4; ++j) {
          const int r = mt * 16 + lg * 4 + j;
          if (r < kN) op[r * kC + cc] = acc[mt][j] + pb;
        }
    }
  }
#undef LDAF
}

// ---------------------------------------------------------------------------
extern "C" void kernel_launch(void* const* d_in, const int* in_sizes, int n_in,
                              void* d_out, int out_size, void* d_ws, size_t ws_size,
                              hipStream_t stream) {
  const float* x          = (const float*)d_in[0];
  const float* mask       = (const float*)d_in[1];
  const float* qkv_w      = (const float*)d_in[2];
  const float* qkv_b      = (const float*)d_in[3];
  const float* proj_w     = (const float*)d_in[4];
  const float* proj_b     = (const float*)d_in[5];
  const float* bias_table = (const float*)d_in[6];
  const int*   rel        = (const int*)d_in[7];

  char* ws = (char*)d_ws;
  __bf16* wq   = (__bf16*)(ws + WQ_OFF);
  __bf16* wp   = (__bf16*)(ws + WP_OFF);
  float* biasp = (float*)(ws + BP_OFF);
  int*   mf    = (int*)(ws + MF_OFF);

  prep_kernel<<<104, 256, 0, stream>>>(qkv_w, proj_w, bias_table, rel, mask,
                                       wq, wp, biasp, mf);
  wattn_fused<<<kB, 256, 0, stream>>>(x, qkv_b, proj_b, wq, wp, biasp, mask,
                                      mf, (float*)d_out);
}

// Round 6
// 109.285 us; speedup vs baseline: 1.4005x; 1.0024x over previous
//
#include <hip/hip_runtime.h>
#include <hip/hip_bf16.h>

typedef __bf16 bf16x8 __attribute__((ext_vector_type(8)));
typedef __bf16 bf16x4 __attribute__((ext_vector_type(4)));
typedef float f32x4 __attribute__((ext_vector_type(4)));

#define MFMA16(a, b, c) __builtin_amdgcn_mfma_f32_16x16x32_bf16((a), (b), (c), 0, 0, 0)

constexpr int kB = 4096, kN = 49, kC = 128;
constexpr float kScale = 0.17677669529663687f;  // 32^-0.5

// workspace layout (bytes)
constexpr size_t WQ_OFF = 0;        // qkv_w packed bf16: [24][4][64][8] = 98304 B
constexpr size_t WP_OFF = 98304;    // proj_w packed bf16: [8][4][64][8] = 32768 B
constexpr size_t BP_OFF = 131072;   // bias f32 [4][64 tok][64 key] (-1e30 at key>=49) = 64 KB
constexpr size_t MF_OFF = 196608;   // mask-nonzero flags: 8 ints

// ---------------------------------------------------------------------------
// prep: pack weights bf16 fragment-linear (serves both A- and B-frag roles);
// build per-head bias table with key-mask folded in; reduce mask to 8 flags.
// ---------------------------------------------------------------------------
__global__ void prep_kernel(const float* __restrict__ qkv_w,
                            const float* __restrict__ proj_w,
                            const float* __restrict__ bias_table,
                            const int* __restrict__ rel_raw,
                            const float* __restrict__ maskp,
                            __bf16* __restrict__ wq, __bf16* __restrict__ wp,
                            float* __restrict__ biasp, int* __restrict__ mf) {
  const int blk = blockIdx.x, t = threadIdx.x;
  // int64-vs-int32 sniff: rel[0]=84 -> int64 word1 is 0; int32 word1 = 83
  const bool is64 = (rel_raw[1] == 0);
  if (blk < 24) {  // qkv_w pack
    const int kk = t >> 6, lane = t & 63;
    const int k0 = kk * 32 + ((lane >> 4) << 3);
    const int c  = blk * 16 + (lane & 15);
#pragma unroll
    for (int i = 0; i < 8; ++i)
      wq[((blk * 4 + kk) * 64 + lane) * 8 + i] = (__bf16)qkv_w[(k0 + i) * 384 + c];
  } else if (blk < 32) {  // proj_w pack
    const int nt = blk - 24;
    const int kk = t >> 6, lane = t & 63;
    const int k0 = kk * 32 + ((lane >> 4) << 3);
    const int c  = nt * 16 + (lane & 15);
#pragma unroll
    for (int i = 0; i < 8; ++i)
      wp[((nt * 4 + kk) * 64 + lane) * 8 + i] = (__bf16)proj_w[(k0 + i) * 128 + c];
  } else if (blk < 96) {  // biasp [h][tok64][key64], key>=49 -> -1e30
    const int e = (blk - 32) * 256 + t;
    const int h = e >> 12, tok = (e >> 6) & 63, key = e & 63;
    float v;
    if (key >= kN) v = -1e30f;
    else if (tok >= kN) v = 0.f;
    else {
      const int flat = tok * kN + key;
      const int idx = is64 ? rel_raw[2 * flat] : rel_raw[flat];
      v = bias_table[idx * 4 + h];
    }
    biasp[(h * 64 + tok) * 64 + key] = v;
  } else {  // blk 96..103: mask nonzero flag (64*49*49 = 153664 elems)
    const int base = (blk - 96) * 19208;
    int any = 0;
    for (int e = base + t; e < base + 19208; e += 256)
      any |= (__float_as_uint(maskp[e]) != 0u) ? 1 : 0;
    const int blkany = __syncthreads_or(any);
    if (t == 0) mf[blk - 96] = blkany;
  }
}

// ---------------------------------------------------------------------------
// lg-group redistribution (verified R4): tiles hold M[idx = src16*16 + lg*4+j]
// at lane lm, packed as uint2; produce frag layout M[idx = lg*8 + i] (bf16x8).
// ---------------------------------------------------------------------------
__device__ __forceinline__ uint2 pack4(f32x4 v) {
  bf16x4 h;
  h[0] = (__bf16)v[0]; h[1] = (__bf16)v[1]; h[2] = (__bf16)v[2]; h[3] = (__bf16)v[3];
  return *(uint2*)&h;
}

__device__ __forceinline__ bf16x8 redis(uint2 p0, uint2 p1, int lane) {
  const int base = (lane & 15) + ((lane >> 4) & 1) * 32;
  const bool hi = lane >= 32;
  unsigned a, b;
  uint4 w;
  a = __shfl((int)p0.x, base);      b = __shfl((int)p1.x, base);      w.x = hi ? b : a;
  a = __shfl((int)p0.y, base);      b = __shfl((int)p1.y, base);      w.y = hi ? b : a;
  a = __shfl((int)p0.x, base + 16); b = __shfl((int)p1.x, base + 16); w.z = hi ? b : a;
  a = __shfl((int)p0.y, base + 16); b = __shfl((int)p1.y, base + 16); w.w = hi ? b : a;
  return *(bf16x8*)&w;
}

// ---------------------------------------------------------------------------
// fused window attention: 1 block = 1 window, 4 waves = 4 heads.
// x staged once in LDS (A-frags read transiently), attention register-resident,
// 2 barriers. Rows 49-63 replicate row 48; -1e30 bias kills padded keys.
// ---------------------------------------------------------------------------
__global__ __launch_bounds__(256, 4)
void wattn_fused(const float* __restrict__ x, const float* __restrict__ qkv_b,
                 const float* __restrict__ proj_b,
                 const __bf16* __restrict__ wq, const __bf16* __restrict__ wp,
                 const float* __restrict__ biasp, const float* __restrict__ mask,
                 const int* __restrict__ mf, float* __restrict__ out) {
  constexpr int XS = 136, OBS = 136;
  __shared__ __align__(16) __bf16 xb[64 * XS];  // 17408 B
  __shared__ __align__(16) __bf16 ob[64 * OBS]; // 17408 B

  const int tid = threadIdx.x;
  const int w = tid >> 6, lane = tid & 63, lg = lane >> 4, lm = lane & 15;
  const int b = blockIdx.x;
  const f32x4 zero4 = {0.f, 0.f, 0.f, 0.f};

  const bool hasMask =
      (mf[0] | mf[1] | mf[2] | mf[3] | mf[4] | mf[5] | mf[6] | mf[7]) != 0;

  // ---- stage x -> xb bf16 (rows 49-63 = row 48 replica) ----
  {
    const float* xp = x + (size_t)b * (kN * kC);
#pragma unroll
    for (int i = 0; i < 8; ++i) {
      const int it = tid + i * 256;
      const int row = it >> 5, col = (it & 31) << 2;
      const int sr = row < kN ? row : (kN - 1);
      f32x4 v = *(const f32x4*)(xp + sr * kC + col);
      bf16x4 h;
      h[0] = (__bf16)v[0]; h[1] = (__bf16)v[1]; h[2] = (__bf16)v[2]; h[3] = (__bf16)v[3];
      *(bf16x4*)(xb + row * XS + col) = h;
    }
  }
  __syncthreads();  // B1: xb ready

#define LDAF(tt, kk) (*(const bf16x8*)(xb + ((tt) * 16 + lm) * XS + (kk) * 32 + lg * 8))

  bf16x8 qf[4], kf[4], vf[2][2];

  // ---- Q^T = Wq_h^T x^T  (acc: [dim=dt*16+lg*4+j][tok=lm]) ----
  {
    uint2 pq[2][4];
#pragma unroll
    for (int dt = 0; dt < 2; ++dt) {
      const int ct = 2 * w + dt;
      bf16x8 wf[4];
#pragma unroll
      for (int kk = 0; kk < 4; ++kk)
        wf[kk] = *(const bf16x8*)(wq + ((size_t)(ct * 4 + kk) * 64 + lane) * 8);
      f32x4 qb4 = *(const f32x4*)(qkv_b + w * 32 + dt * 16 + lg * 4);
#pragma unroll
      for (int tt = 0; tt < 4; ++tt) {
        f32x4 acc = zero4;
        __builtin_amdgcn_s_setprio(1);
#pragma unroll
        for (int kk = 0; kk < 4; ++kk) acc = MFMA16(wf[kk], LDAF(tt, kk), acc);
        __builtin_amdgcn_s_setprio(0);
#pragma unroll
        for (int j = 0; j < 4; ++j) acc[j] = (acc[j] + qb4[j]) * kScale;
        pq[dt][tt] = pack4(acc);
      }
    }
#pragma unroll
    for (int tt = 0; tt < 4; ++tt) qf[tt] = redis(pq[0][tt], pq[1][tt], lane);
  }

  // ---- K^T ----
  {
    uint2 pk[2][4];
#pragma unroll
    for (int dt = 0; dt < 2; ++dt) {
      const int ct = 8 + 2 * w + dt;
      bf16x8 wf[4];
#pragma unroll
      for (int kk = 0; kk < 4; ++kk)
        wf[kk] = *(const bf16x8*)(wq + ((size_t)(ct * 4 + kk) * 64 + lane) * 8);
      f32x4 kb4 = *(const f32x4*)(qkv_b + 128 + w * 32 + dt * 16 + lg * 4);
#pragma unroll
      for (int tt = 0; tt < 4; ++tt) {
        f32x4 acc = zero4;
        __builtin_amdgcn_s_setprio(1);
#pragma unroll
        for (int kk = 0; kk < 4; ++kk) acc = MFMA16(wf[kk], LDAF(tt, kk), acc);
        __builtin_amdgcn_s_setprio(0);
#pragma unroll
        for (int j = 0; j < 4; ++j) acc[j] += kb4[j];
        pk[dt][tt] = pack4(acc);
      }
    }
#pragma unroll
    for (int kt = 0; kt < 4; ++kt) kf[kt] = redis(pk[0][kt], pk[1][kt], lane);
  }

  // ---- V = x Wv (acc: [tok=mt*16+lg*4+j][d=dt*16+lm]) ----
  {
    uint2 pv[4][2];
#pragma unroll
    for (int dt = 0; dt < 2; ++dt) {
      const int ct = 16 + 2 * w + dt;
      bf16x8 wf[4];
#pragma unroll
      for (int kk = 0; kk < 4; ++kk)
        wf[kk] = *(const bf16x8*)(wq + ((size_t)(ct * 4 + kk) * 64 + lane) * 8);
      const float vb = qkv_b[256 + w * 32 + dt * 16 + lm];
#pragma unroll
      for (int mt = 0; mt < 4; ++mt) {
        f32x4 acc = zero4;
        __builtin_amdgcn_s_setprio(1);
#pragma unroll
        for (int kk = 0; kk < 4; ++kk) acc = MFMA16(LDAF(mt, kk), wf[kk], acc);
        __builtin_amdgcn_s_setprio(0);
#pragma unroll
        for (int j = 0; j < 4; ++j) acc[j] += vb;
        pv[mt][dt] = pack4(acc);
      }
    }
#pragma unroll
    for (int k2 = 0; k2 < 2; ++k2)
#pragma unroll
      for (int dt = 0; dt < 2; ++dt)
        vf[k2][dt] = redis(pv[k2 * 2][dt], pv[k2 * 2 + 1][dt], lane);
  }

  // ---- attention: S^T = K·Q^T (+bias table incl. key mask), softmax, PV ----
  const float* bpp = biasp + w * 4096;
  const float* mkp = mask + (size_t)(b & 63) * (kN * kN);

#pragma unroll
  for (int tt = 0; tt < 4; ++tt) {
    f32x4 st[4];
    __builtin_amdgcn_s_setprio(1);
#pragma unroll
    for (int kt = 0; kt < 4; ++kt) st[kt] = MFMA16(kf[kt], qf[tt], zero4);
    __builtin_amdgcn_s_setprio(0);
    const int tok = tt * 16 + lm;
#pragma unroll
    for (int kt = 0; kt < 4; ++kt) {
      f32x4 bm = *(const f32x4*)(bpp + (tok << 6) + kt * 16 + lg * 4);
#pragma unroll
      for (int j = 0; j < 4; ++j) st[kt][j] += bm[j];
    }
    if (hasMask) {
      const int tok2 = tok < kN ? tok : (kN - 1);
#pragma unroll
      for (int kt = 0; kt < 4; ++kt)
#pragma unroll
        for (int j = 0; j < 4; ++j) {
          const int key = kt * 16 + lg * 4 + j;
          const int key2 = key < kN ? key : (kN - 1);
          st[kt][j] += mkp[tok2 * kN + key2];
        }
    }
    // softmax over keys (keys on (kt,lg,j); token on lm)
    float m = -3e38f;
#pragma unroll
    for (int kt = 0; kt < 4; ++kt)
#pragma unroll
      for (int j = 0; j < 4; ++j) m = fmaxf(m, st[kt][j]);
    m = fmaxf(m, __shfl_xor(m, 16));
    m = fmaxf(m, __shfl_xor(m, 32));
    float sum = 0.f;
#pragma unroll
    for (int kt = 0; kt < 4; ++kt)
#pragma unroll
      for (int j = 0; j < 4; ++j) {
        const float e = __expf(st[kt][j] - m);
        st[kt][j] = e;
        sum += e;
      }
    sum += __shfl_xor(sum, 16);
    sum += __shfl_xor(sum, 32);
    const float rs = 1.f / sum;
    uint2 pst[4];
#pragma unroll
    for (int kt = 0; kt < 4; ++kt) {
      f32x4 t;
#pragma unroll
      for (int j = 0; j < 4; ++j) t[j] = st[kt][j] * rs;
      pst[kt] = pack4(t);
    }
    bf16x8 pa0 = redis(pst[0], pst[1], lane);
    bf16x8 pa1 = redis(pst[2], pst[3], lane);
#pragma unroll
    for (int dt = 0; dt < 2; ++dt) {
      f32x4 o = MFMA16(pa0, vf[0][dt], zero4);
      o = MFMA16(pa1, vf[1][dt], o);
#pragma unroll
      for (int j = 0; j < 4; ++j)
        ob[(tt * 16 + lg * 4 + j) * OBS + w * 32 + dt * 16 + lm] = (__bf16)o[j];
    }
  }
  __syncthreads();  // B2: ob ready

  // ---- proj GEMM [64x128]@[128x128] + bias -> out (f32) ----
  {
    float* op = out + (size_t)b * (kN * kC);
#pragma unroll
    for (int n = 0; n < 2; ++n) {
      bf16x8 wpb[4];
#pragma unroll
      for (int kk = 0; kk < 4; ++kk)
        wpb[kk] = *(const bf16x8*)(wp + (size_t)(((w * 2 + n) * 4 + kk) * 64 + lane) * 8);
      f32x4 acc[4];
#pragma unroll
      for (int mt = 0; mt < 4; ++mt) acc[mt] = zero4;
#pragma unroll
      for (int kk = 0; kk < 4; ++kk) {
        __builtin_amdgcn_s_setprio(1);
#pragma unroll
        for (int mt = 0; mt < 4; ++mt)
          acc[mt] = MFMA16(*(const bf16x8*)(ob + (mt * 16 + lm) * OBS + kk * 32 + lg * 8),
                           wpb[kk], acc[mt]);
        __builtin_amdgcn_s_setprio(0);
      }
      const int cc = (w * 2 + n) * 16 + lm;
      const float pb = proj_b[cc];
#pragma unroll
      for (int mt = 0; mt < 4; ++mt)
#pragma unroll
        for (int j = 0; j < 4; ++j) {
          const int r = mt * 16 + lg * 4 + j;
          if (r < kN) op[r * kC + cc] = acc[mt][j] + pb;
        }
    }
  }
#undef LDAF
}

// ---------------------------------------------------------------------------
extern "C" void kernel_launch(void* const* d_in, const int* in_sizes, int n_in,
                              void* d_out, int out_size, void* d_ws, size_t ws_size,
                              hipStream_t stream) {
  const float* x          = (const float*)d_in[0];
  const float* mask       = (const float*)d_in[1];
  const float* qkv_w      = (const float*)d_in[2];
  const float* qkv_b      = (const float*)d_in[3];
  const float* proj_w     = (const float*)d_in[4];
  const float* proj_b     = (const float*)d_in[5];
  const float* bias_table = (const float*)d_in[6];
  const int*   rel        = (const int*)d_in[7];

  char* ws = (char*)d_ws;
  __bf16* wq   = (__bf16*)(ws + WQ_OFF);
  __bf16* wp   = (__bf16*)(ws + WP_OFF);
  float* biasp = (float*)(ws + BP_OFF);
  int*   mf    = (int*)(ws + MF_OFF);

  prep_kernel<<<104, 256, 0, stream>>>(qkv_w, proj_w, bias_table, rel, mask,
                                       wq, wp, biasp, mf);
  wattn_fused<<<kB, 256, 0, stream>>>(x, qkv_b, proj_b, wq, wp, biasp, mask,
                                      mf, (float*)d_out);
}